// Round 1
// baseline (14946.597 us; speedup 1.0000x reference)
//
#include <hip/hip_runtime.h>
#include <math.h>

#define T_LEN 20000
#define KST 64
#define KP1 65
#define DD 32

static __device__ __forceinline__ float wsum64(float v){
  v += __shfl_xor(v, 1);  v += __shfl_xor(v, 2);  v += __shfl_xor(v, 4);
  v += __shfl_xor(v, 8);  v += __shfl_xor(v, 16); v += __shfl_xor(v, 32);
  return v;
}
static __device__ __forceinline__ float wmax64(float v){
  v = fmaxf(v, __shfl_xor(v, 1));  v = fmaxf(v, __shfl_xor(v, 2));  v = fmaxf(v, __shfl_xor(v, 4));
  v = fmaxf(v, __shfl_xor(v, 8));  v = fmaxf(v, __shfl_xor(v, 16)); v = fmaxf(v, __shfl_xor(v, 32));
  return v;
}
// digamma via recurrence + asymptotic series (accurate to ~1e-7 rel for x>0)
static __device__ __forceinline__ float digamma_f(float x){
  float r = 0.f;
  while (x < 6.f){ r -= 1.f / x; x += 1.f; }
  float xi = 1.f / x;
  float xi2 = xi * xi;
  return r + logf(x) - 0.5f * xi
       - xi2 * (0.08333333333f - xi2 * (0.008333333333f - xi2 * 0.003968253968f));
}
static __device__ __forceinline__ float rcp_nr(float s){
  float r = __builtin_amdgcn_rcpf(s);
  return r * (2.0f - s * r);   // one Newton step
}

// ---------------- per-component prep: Cholesky, inverse, E_logdet ----------------
__global__ void prep_k(const float* __restrict__ mu, const float* __restrict__ kappa,
                       const float* __restrict__ nu, const float* __restrict__ Psi,
                       float* __restrict__ Lam, float* __restrict__ dLam,
                       float* __restrict__ constk){
  const int k = blockIdx.x, tid = threadIdx.x;
  __shared__ float P[DD][DD + 1];
  const float* Pk = Psi + k * DD * DD;
  for (int e = tid; e < DD * DD; e += 64) P[e / DD][e % DD] = Pk[e];
  __syncthreads();
  // in-place Cholesky (lower)
  for (int c = 0; c < DD; ++c){
    if (tid == c){
      float s = P[c][c];
      for (int m = 0; m < c; ++m) s -= P[c][m] * P[c][m];
      P[c][c] = sqrtf(s);
    }
    __syncthreads();
    if (tid > c && tid < DD){
      float s = P[tid][c];
      for (int m = 0; m < c; ++m) s -= P[tid][m] * P[c][m];
      P[tid][c] = s / P[c][c];
    }
    __syncthreads();
  }
  const float nuk = nu[k];
  // thread j (<32) solves Psi x = e_j via two triangular solves -> column j of inv(Psi)
  if (tid < DD){
    float y[DD];
    #pragma unroll
    for (int r2 = 0; r2 < DD; ++r2){
      float s = (r2 == tid) ? 1.f : 0.f;
      #pragma unroll
      for (int m = 0; m < r2; ++m) s -= P[r2][m] * y[m];
      y[r2] = s / P[r2][r2];
    }
    #pragma unroll
    for (int r2 = DD - 1; r2 >= 0; --r2){
      float s = y[r2];
      #pragma unroll
      for (int m = r2 + 1; m < DD; ++m) s -= P[m][r2] * y[m];
      y[r2] = s / P[r2][r2];
    }
    #pragma unroll
    for (int i = 0; i < DD; ++i) Lam[k * DD * DD + i * DD + tid] = nuk * y[i];
    dLam[k * DD + tid] = nuk * y[tid];
  }
  float dg = 0.f, ld = 0.f;
  if (tid < DD){
    dg = digamma_f((nuk + 1.f - (float)(tid + 1)) * 0.5f);
    ld = logf(P[tid][tid]);
  }
  dg = wsum64(dg);
  ld = wsum64(ld);
  if (tid == 0){
    const float LOG2 = 0.6931471805599453f, LOG2PI = 1.8378770664093453f;
    float logdet = 2.f * ld;
    float Elogdet = dg - DD * LOG2 - logdet;
    float t3 = DD * nuk / (kappa[k] * fmaxf(nuk - DD - 1.f, 1.f));
    constk[k] = -0.5f * (Elogdet + t3 + DD * LOG2PI);
  }
}

// ---------------- transition prep: log_A, M = [exp(log_A); pi+eps], log_pi ----------------
__global__ void prep_trans(const float* __restrict__ phi, const float* __restrict__ pi_star,
                           float* __restrict__ M, float* __restrict__ logA,
                           float* __restrict__ logpi){
  const int i = threadIdx.x;  // 64 rows
  float rs = 0.f;
  for (int j = 0; j < KP1; ++j) rs += phi[i * KP1 + j];
  float dgs = digamma_f(rs);
  for (int j = 0; j < KP1; ++j){
    float la = digamma_f(phi[i * KP1 + j]) - dgs;
    logA[i * KP1 + j] = la;
    M[i * KP1 + j] = expf(la);
  }
  if (i == 0){
    for (int j = 0; j < KP1; ++j){
      float pe = pi_star[j] + 1e-9f;
      logpi[j] = logf(pe);
      M[KST * KP1 + j] = pe;
    }
  }
}

// ---------------- emission log-likelihoods log_B (T x Kp1) ----------------
__global__ void logb_k(const float* __restrict__ zmu, const float* __restrict__ zvar,
                       const float* __restrict__ mu, const float* __restrict__ Lam,
                       const float* __restrict__ dLam, const float* __restrict__ constk,
                       float* __restrict__ logB){
  const int k = blockIdx.y, tid = threadIdx.x;
  const int t = blockIdx.x * 256 + tid;
  __shared__ float Ls[DD * DD];
  __shared__ float mus[DD], dls[DD];
  for (int e = tid; e < DD * DD; e += 256) Ls[e] = Lam[k * DD * DD + e];
  if (tid < DD){ mus[tid] = mu[k * DD + tid]; dls[tid] = dLam[k * DD + tid]; }
  __syncthreads();
  if (t >= T_LEN) return;
  const float4* zm4 = reinterpret_cast<const float4*>(zmu + (size_t)t * DD);
  const float4* zv4 = reinterpret_cast<const float4*>(zvar + (size_t)t * DD);
  float d[DD];
  float acc1 = 0.f;
  #pragma unroll
  for (int q = 0; q < DD / 4; ++q){
    float4 vm = zm4[q]; float4 vv = zv4[q];
    d[4*q+0] = vm.x - mus[4*q+0];
    d[4*q+1] = vm.y - mus[4*q+1];
    d[4*q+2] = vm.z - mus[4*q+2];
    d[4*q+3] = vm.w - mus[4*q+3];
    acc1 = fmaf(dls[4*q+0], vv.x, acc1);
    acc1 = fmaf(dls[4*q+1], vv.y, acc1);
    acc1 = fmaf(dls[4*q+2], vv.z, acc1);
    acc1 = fmaf(dls[4*q+3], vv.w, acc1);
  }
  float acc2 = 0.f;
  #pragma unroll
  for (int i = 0; i < DD; ++i){
    float s = 0.f;
    #pragma unroll
    for (int j = 0; j < DD; ++j) s = fmaf(Ls[i * DD + j], d[j], s);
    acc2 = fmaf(s, d[i], acc2);
  }
  logB[(size_t)t * KP1 + k] = constk[k] - 0.5f * (acc1 + acc2);
}

// ---------------- per-row max + Bexp = exp(logB - max) ----------------
__global__ void bexp_k(const float* __restrict__ logB, float* __restrict__ Bexp,
                       float* __restrict__ bmax){
  const int lane = threadIdx.x & 63, w = threadIdx.x >> 6;
  const int t = blockIdx.x * 4 + w;
  if (t >= T_LEN) return;
  float v = logB[(size_t)t * KP1 + lane];
  float v64 = logB[(size_t)t * KP1 + 64];
  float m = fmaxf(wmax64(v), v64);
  Bexp[(size_t)t * KP1 + lane] = expf(v - m);
  if (lane == 0){ Bexp[(size_t)t * KP1 + 64] = expf(v64 - m); bmax[t] = m; }
}

// ---------------- sequential scans: block 0 = forward, block 1 = backward ----------------
struct RowB { float bx, b64, bm; };

__global__ __launch_bounds__(64) void scan_k(const float* __restrict__ M,
    const float* __restrict__ Bexp, const float* __restrict__ bmax,
    float* __restrict__ pstore, float* __restrict__ qstore,
    float* __restrict__ cfor, float* __restrict__ cbwd, float* __restrict__ logZout){
  const int lane = threadIdx.x;
  __shared__ __align__(16) float pS[68];
  auto loadRow = [&](int t) -> RowB {
    RowB r;
    r.bx  = Bexp[(size_t)t * KP1 + lane];
    r.b64 = Bexp[(size_t)t * KP1 + 64];
    r.bm  = bmax[t];
    return r;
  };
  if (blockIdx.x == 0){
    // ---------------- forward ----------------
    float Mreg[KP1];               // column `lane` of M
    #pragma unroll
    for (int i = 0; i < KP1; ++i) Mreg[i] = M[i * KP1 + lane];
    const float M64c  = M[lane * KP1 + 64];  // M[lane][64]
    const float M6464 = M[KST * KP1 + 64];
    float p_j = 0.f, p64 = 0.f, C = 0.f;
    auto finishF = [&](int t, RowB rw, float msg, float msg64){
      float val   = rw.bx * msg;
      float val64 = rw.b64 * msg64;
      float s_tot = wsum64(val) + val64;
      float r = rcp_nr(s_tot);
      p_j = val * r; p64 = val64 * r;
      pS[lane] = p_j;
      if (lane == 0) pS[64] = p64;
      __syncthreads();
      pstore[(size_t)t * KP1 + lane] = p_j;
      if (lane == 0) pstore[(size_t)t * KP1 + 64] = p64;
      C += logf(s_tot) + rw.bm;
      if (lane == 0) cfor[t] = C;
    };
    auto stepF = [&](int t, RowB rw){
      const float4* pS4 = reinterpret_cast<const float4*>(pS);
      float msg = 0.f;
      #pragma unroll
      for (int q = 0; q < 16; ++q){
        float4 pv = pS4[q];
        msg = fmaf(pv.x, Mreg[4*q+0], msg);
        msg = fmaf(pv.y, Mreg[4*q+1], msg);
        msg = fmaf(pv.z, Mreg[4*q+2], msg);
        msg = fmaf(pv.w, Mreg[4*q+3], msg);
      }
      msg = fmaf(pS[64], Mreg[64], msg);
      float partial = p_j * M64c;
      float msg64 = wsum64(partial) + p64 * M6464;
      finishF(t, rw, msg, msg64);
    };
    finishF(0, loadRow(0), Mreg[64], M6464);   // t = 0: alpha0 = pi .* B0
    RowB rA = loadRow(1), rB = loadRow(2), rC = loadRow(3), rD = loadRow(4);
    int t = 1;
    for (; t + 3 < T_LEN; t += 4){
      RowB n;
      n = loadRow(min(t + 4, T_LEN - 1)); stepF(t,     rA); rA = n;
      n = loadRow(min(t + 5, T_LEN - 1)); stepF(t + 1, rB); rB = n;
      n = loadRow(min(t + 6, T_LEN - 1)); stepF(t + 2, rC); rC = n;
      n = loadRow(min(t + 7, T_LEN - 1)); stepF(t + 3, rD); rD = n;
    }
    for (; t < T_LEN; ++t) stepF(t, loadRow(t));
    if (lane == 0) logZout[0] = C;
  } else {
    // ---------------- backward ----------------
    float Mrow[KP1];               // row `lane` of M
    #pragma unroll
    for (int j = 0; j < KP1; ++j) Mrow[j] = M[lane * KP1 + j];
    const float P64row = M[KST * KP1 + lane];
    const float P6464  = M[KST * KP1 + 64];
    float q_j = 1.f / 65.f, q64 = 1.f / 65.f, Dc = logf(65.f);
    qstore[(size_t)(T_LEN - 1) * KP1 + lane] = q_j;
    if (lane == 0){ qstore[(size_t)(T_LEN - 1) * KP1 + 64] = q64; cbwd[T_LEN - 1] = Dc; }
    auto stepB = [&](int t, RowB rw){   // rw = row t+1
      float x   = rw.bx * q_j;
      float x64 = rw.b64 * q64;
      pS[lane] = x;
      __syncthreads();
      const float4* xS4 = reinterpret_cast<const float4*>(pS);
      float nq = 0.f;
      #pragma unroll
      for (int q = 0; q < 16; ++q){
        float4 xv = xS4[q];
        nq = fmaf(xv.x, Mrow[4*q+0], nq);
        nq = fmaf(xv.y, Mrow[4*q+1], nq);
        nq = fmaf(xv.z, Mrow[4*q+2], nq);
        nq = fmaf(xv.w, Mrow[4*q+3], nq);
      }
      nq = fmaf(x64, Mrow[64], nq);
      float partial = x * P64row;
      float q64new = wsum64(partial) + P6464 * x64;
      float s_tot = wsum64(nq) + q64new;
      float r = rcp_nr(s_tot);
      q_j = nq * r; q64 = q64new * r;
      qstore[(size_t)t * KP1 + lane] = q_j;
      if (lane == 0) qstore[(size_t)t * KP1 + 64] = q64;
      Dc += logf(s_tot) + rw.bm;
      if (lane == 0) cbwd[t] = Dc;
    };
    RowB rA = loadRow(T_LEN - 1), rB = loadRow(T_LEN - 2),
         rC = loadRow(T_LEN - 3), rD = loadRow(T_LEN - 4);
    int t = T_LEN - 2;
    for (; t - 3 >= 0; t -= 4){
      RowB n;
      n = loadRow(max(t - 3, 1)); stepB(t,     rA); rA = n;
      n = loadRow(max(t - 4, 1)); stepB(t - 1, rB); rB = n;
      n = loadRow(max(t - 5, 1)); stepB(t - 2, rC); rC = n;
      n = loadRow(max(t - 6, 1)); stepB(t - 3, rD); rD = n;
    }
    for (; t >= 0; --t) stepB(t, loadRow(t + 1));
  }
}

// ---------------- gamma: softmax(log p + log q), scales cancel ----------------
__global__ void gamma_k(const float* __restrict__ pstore, const float* __restrict__ qstore,
                        float* __restrict__ gout){
  const int lane = threadIdx.x & 63, w = threadIdx.x >> 6;
  const int t = blockIdx.x * 4 + w;
  if (t >= T_LEN) return;
  float a   = pstore[(size_t)t * KP1 + lane] * qstore[(size_t)t * KP1 + lane];
  float a64 = pstore[(size_t)t * KP1 + 64]   * qstore[(size_t)t * KP1 + 64];
  float s = wsum64(a) + a64;
  float r = rcp_nr(s);
  gout[(size_t)t * KP1 + lane] = a * r;
  if (lane == 0) gout[(size_t)t * KP1 + 64] = a64 * r;
}

// ---------------- xi: per-t softmax over (K x Kp1) of reference's temp ----------------
__global__ void xi_k(const float* __restrict__ pstore, const float* __restrict__ qstore,
                     const float* __restrict__ logB, const float* __restrict__ cfor,
                     const float* __restrict__ logA, const float* __restrict__ logpi,
                     float* __restrict__ xiout){
  const int t = blockIdx.x, tid = threadIdx.x;
  __shared__ float laS[64], bbS[KP1], lpiS[KP1];
  __shared__ float red[4], red2[4];
  if (tid < 64){
    laS[tid] = logf(pstore[(size_t)t * KP1 + tid]) + cfor[t];
  } else if (tid < 64 + KP1){
    int j = tid - 64;
    bbS[j] = logB[(size_t)(t + 1) * KP1 + j] + logf(qstore[(size_t)(t + 1) * KP1 + j]);
  } else if (tid < 64 + 2 * KP1){
    int j = tid - (64 + KP1);
    lpiS[j] = logpi[j];
  }
  __syncthreads();
  float tv[17];
  float lm = -3.0e38f;
  #pragma unroll
  for (int r2 = 0; r2 < 17; ++r2){
    int e = tid + 256 * r2;
    if (e < KST * KP1){
      int i = e / KP1;
      int j = e - i * KP1;
      float a = laS[i] + logA[e];
      float b = lpiS[j];
      float mx = fmaxf(a, b), mn = fminf(a, b);
      float v = bbS[j] + mx + log1pf(expf(mn - mx));
      tv[r2] = v;
      lm = fmaxf(lm, v);
    } else tv[r2] = -3.0e38f;
  }
  lm = wmax64(lm);
  if ((tid & 63) == 0) red[tid >> 6] = lm;
  __syncthreads();
  float gm = fmaxf(fmaxf(red[0], red[1]), fmaxf(red[2], red[3]));
  float se = 0.f;
  #pragma unroll
  for (int r2 = 0; r2 < 17; ++r2) se += expf(tv[r2] - gm);
  se = wsum64(se);
  if ((tid & 63) == 0) red2[tid >> 6] = se;
  __syncthreads();
  float S = red2[0] + red2[1] + red2[2] + red2[3];
  float rS = rcp_nr(S);
  float* xrow = xiout + (size_t)t * (KST * KP1);
  #pragma unroll
  for (int r2 = 0; r2 < 17; ++r2){
    int e = tid + 256 * r2;
    if (e < KST * KP1) xrow[e] = expf(tv[r2] - gm) * rS;
  }
}

extern "C" void kernel_launch(void* const* d_in, const int* in_sizes, int n_in,
                              void* d_out, int out_size, void* d_ws, size_t ws_size,
                              hipStream_t stream){
  const float* z_mu  = (const float*)d_in[0];
  const float* z_var = (const float*)d_in[1];
  const float* mu    = (const float*)d_in[2];
  const float* kappa = (const float*)d_in[3];
  const float* nu    = (const float*)d_in[4];
  const float* Psi   = (const float*)d_in[5];
  const float* phi   = (const float*)d_in[6];
  const float* pis   = (const float*)d_in[7];
  float* out = (float*)d_out;

  float* ws     = (float*)d_ws;
  float* Lam    = ws;                  // 65*1024 = 66560
  float* dLam   = Lam + 66560;         // 2080
  float* constk = dLam + 2080;         // 65
  float* M      = constk + 65;         // 4225
  float* logA   = M + 4225;            // 4225
  float* logpi  = logA + 4225;         // 65
  float* logB   = logpi + 65;          // 1,300,000
  float* Bexp   = logB + 1300000;      // 1,300,000
  float* bmax   = Bexp + 1300000;      // 20,000
  float* pstore = bmax + 20000;        // 1,300,000
  float* qstore = pstore + 1300000;    // 1,300,000
  float* cfor   = qstore + 1300000;    // 20,000
  float* cbwd   = cfor + 20000;        // 20,000
  // total = 5,337,220 floats ~ 20.4 MiB of d_ws

  float* gammaOut = out;
  float* xiOut    = out + (size_t)T_LEN * KP1;
  float* logZOut  = xiOut + (size_t)(T_LEN - 1) * KST * KP1;

  prep_k<<<KP1, 64, 0, stream>>>(mu, kappa, nu, Psi, Lam, dLam, constk);
  prep_trans<<<1, 64, 0, stream>>>(phi, pis, M, logA, logpi);
  logb_k<<<dim3((T_LEN + 255) / 256, KP1), 256, 0, stream>>>(z_mu, z_var, mu, Lam, dLam, constk, logB);
  bexp_k<<<(T_LEN + 3) / 4, 256, 0, stream>>>(logB, Bexp, bmax);
  scan_k<<<2, 64, 0, stream>>>(M, Bexp, bmax, pstore, qstore, cfor, cbwd, logZOut);
  gamma_k<<<(T_LEN + 3) / 4, 256, 0, stream>>>(pstore, qstore, gammaOut);
  xi_k<<<T_LEN - 1, 256, 0, stream>>>(pstore, qstore, logB, cfor, logA, logpi, xiOut);
}

// Round 2
// 1365.012 us; speedup vs baseline: 10.9498x; 10.9498x over previous
//
#include <hip/hip_runtime.h>
#include <math.h>

#define T_LEN 20000
#define KST 64
#define KP1 65
#define DD 32
#define CHK 250
#define LCH 80

static __device__ __forceinline__ float wsum64(float v){
  v += __shfl_xor(v, 1);  v += __shfl_xor(v, 2);  v += __shfl_xor(v, 4);
  v += __shfl_xor(v, 8);  v += __shfl_xor(v, 16); v += __shfl_xor(v, 32);
  return v;
}
static __device__ __forceinline__ float wmax64(float v){
  v = fmaxf(v, __shfl_xor(v, 1));  v = fmaxf(v, __shfl_xor(v, 2));  v = fmaxf(v, __shfl_xor(v, 4));
  v = fmaxf(v, __shfl_xor(v, 8));  v = fmaxf(v, __shfl_xor(v, 16)); v = fmaxf(v, __shfl_xor(v, 32));
  return v;
}
static __device__ __forceinline__ float readlane_f(float v, int i){
  return __int_as_float(__builtin_amdgcn_readlane(__float_as_int(v), i));
}
static __device__ __forceinline__ float digamma_f(float x){
  float r = 0.f;
  while (x < 6.f){ r -= 1.f / x; x += 1.f; }
  float xi = 1.f / x;
  float xi2 = xi * xi;
  return r + logf(x) - 0.5f * xi
       - xi2 * (0.08333333333f - xi2 * (0.008333333333f - xi2 * 0.003968253968f));
}
static __device__ __forceinline__ float rcp_nr(float s){
  float r = __builtin_amdgcn_rcpf(s);
  return r * (2.0f - s * r);
}

// ---------------- per-component prep: Cholesky, inverse, E_logdet ----------------
__global__ void prep_k(const float* __restrict__ mu, const float* __restrict__ kappa,
                       const float* __restrict__ nu, const float* __restrict__ Psi,
                       float* __restrict__ Lam, float* __restrict__ dLam,
                       float* __restrict__ constk){
  const int k = blockIdx.x, tid = threadIdx.x;
  __shared__ float P[DD][DD + 1];
  const float* Pk = Psi + k * DD * DD;
  for (int e = tid; e < DD * DD; e += 64) P[e / DD][e % DD] = Pk[e];
  __syncthreads();
  for (int c = 0; c < DD; ++c){
    if (tid == c){
      float s = P[c][c];
      for (int m = 0; m < c; ++m) s -= P[c][m] * P[c][m];
      P[c][c] = sqrtf(s);
    }
    __syncthreads();
    if (tid > c && tid < DD){
      float s = P[tid][c];
      for (int m = 0; m < c; ++m) s -= P[tid][m] * P[c][m];
      P[tid][c] = s / P[c][c];
    }
    __syncthreads();
  }
  const float nuk = nu[k];
  if (tid < DD){
    float y[DD];
    #pragma unroll
    for (int r2 = 0; r2 < DD; ++r2){
      float s = (r2 == tid) ? 1.f : 0.f;
      #pragma unroll
      for (int m = 0; m < r2; ++m) s -= P[r2][m] * y[m];
      y[r2] = s / P[r2][r2];
    }
    #pragma unroll
    for (int r2 = DD - 1; r2 >= 0; --r2){
      float s = y[r2];
      #pragma unroll
      for (int m = r2 + 1; m < DD; ++m) s -= P[m][r2] * y[m];
      y[r2] = s / P[r2][r2];
    }
    #pragma unroll
    for (int i = 0; i < DD; ++i) Lam[k * DD * DD + i * DD + tid] = nuk * y[i];
    dLam[k * DD + tid] = nuk * y[tid];
  }
  float dg = 0.f, ld = 0.f;
  if (tid < DD){
    dg = digamma_f((nuk + 1.f - (float)(tid + 1)) * 0.5f);
    ld = logf(P[tid][tid]);
  }
  dg = wsum64(dg);
  ld = wsum64(ld);
  if (tid == 0){
    const float LOG2 = 0.6931471805599453f, LOG2PI = 1.8378770664093453f;
    float logdet = 2.f * ld;
    float Elogdet = dg - DD * LOG2 - logdet;
    float t3 = DD * nuk / (kappa[k] * fmaxf(nuk - DD - 1.f, 1.f));
    constk[k] = -0.5f * (Elogdet + t3 + DD * LOG2PI);
  }
}

// ---------------- transition prep ----------------
// M_mat[i*68+j] = M[i][j] (row 64 = pi+eps), MT[j*68+i] = M[i][j]  (i.e. MT[a][b] = M[b][a])
__global__ void prep_trans(const float* __restrict__ phi, const float* __restrict__ pi_star,
                           float* __restrict__ M_mat, float* __restrict__ MT,
                           float* __restrict__ logA, float* __restrict__ logpi){
  const int i = threadIdx.x;  // 64 rows
  float rs = 0.f;
  for (int j = 0; j < KP1; ++j) rs += phi[i * KP1 + j];
  float dgs = digamma_f(rs);
  for (int j = 0; j < KP1; ++j){
    float la = digamma_f(phi[i * KP1 + j]) - dgs;
    logA[i * KP1 + j] = la;
    float e = expf(la);
    M_mat[i * 68 + j] = e;
    MT[j * 68 + i] = e;
  }
  if (i == 0){
    for (int j = 0; j < KP1; ++j){
      float pe = pi_star[j] + 1e-9f;
      logpi[j] = logf(pe);
      M_mat[64 * 68 + j] = pe;
      MT[j * 68 + 64] = pe;
    }
  }
}

// ---------------- emission log-likelihoods log_B (T x Kp1) ----------------
__global__ void logb_k(const float* __restrict__ zmu, const float* __restrict__ zvar,
                       const float* __restrict__ mu, const float* __restrict__ Lam,
                       const float* __restrict__ dLam, const float* __restrict__ constk,
                       float* __restrict__ logB){
  const int k = blockIdx.y, tid = threadIdx.x;
  const int t = blockIdx.x * 256 + tid;
  __shared__ float Ls[DD * DD];
  __shared__ float mus[DD], dls[DD];
  for (int e = tid; e < DD * DD; e += 256) Ls[e] = Lam[k * DD * DD + e];
  if (tid < DD){ mus[tid] = mu[k * DD + tid]; dls[tid] = dLam[k * DD + tid]; }
  __syncthreads();
  if (t >= T_LEN) return;
  const float4* zm4 = reinterpret_cast<const float4*>(zmu + (size_t)t * DD);
  const float4* zv4 = reinterpret_cast<const float4*>(zvar + (size_t)t * DD);
  float d[DD];
  float acc1 = 0.f;
  #pragma unroll
  for (int q = 0; q < DD / 4; ++q){
    float4 vm = zm4[q]; float4 vv = zv4[q];
    d[4*q+0] = vm.x - mus[4*q+0];
    d[4*q+1] = vm.y - mus[4*q+1];
    d[4*q+2] = vm.z - mus[4*q+2];
    d[4*q+3] = vm.w - mus[4*q+3];
    acc1 = fmaf(dls[4*q+0], vv.x, acc1);
    acc1 = fmaf(dls[4*q+1], vv.y, acc1);
    acc1 = fmaf(dls[4*q+2], vv.z, acc1);
    acc1 = fmaf(dls[4*q+3], vv.w, acc1);
  }
  float acc2 = 0.f;
  #pragma unroll
  for (int i = 0; i < DD; ++i){
    float s = 0.f;
    #pragma unroll
    for (int q = 0; q < DD/4; ++q){
      float4 L4 = *reinterpret_cast<const float4*>(&Ls[i*DD + q*4]);
      s = fmaf(L4.x, d[q*4+0], s);
      s = fmaf(L4.y, d[q*4+1], s);
      s = fmaf(L4.z, d[q*4+2], s);
      s = fmaf(L4.w, d[q*4+3], s);
    }
    acc2 = fmaf(s, d[i], acc2);
  }
  logB[(size_t)t * KP1 + k] = constk[k] - 0.5f * (acc1 + acc2);
}

// ---------------- per-row max + Bexp = exp(logB - max) ----------------
__global__ void bexp_k(const float* __restrict__ logB, float* __restrict__ Bexp,
                       float* __restrict__ bmax){
  const int lane = threadIdx.x & 63, w = threadIdx.x >> 6;
  const int t = blockIdx.x * 4 + w;
  if (t >= T_LEN) return;
  float v = logB[(size_t)t * KP1 + lane];
  float v64 = logB[(size_t)t * KP1 + 64];
  float m = fmaxf(wmax64(v), v64);
  Bexp[(size_t)t * KP1 + lane] = expf(v - m);
  if (lane == 0){ Bexp[(size_t)t * KP1 + 64] = expf(v64 - m); bmax[t] = m; }
}

// ---------------- phase 1: per-chunk 65x65 operators ----------------
// update: X <- diag(b_r) * M^T * X, r increasing over the chunk's row range.
// main blocks (bx < CHK): columns 0..63, lane = column. service blocks: column 64, lane = k.
// store S[dir][c][i][j] = X[i][j] (4225) then sigma[65].
__global__ __launch_bounds__(64) void p1_k(const float* __restrict__ MT_g,
    const float* __restrict__ Bexp, float* __restrict__ S){
  __shared__ float MTl[65 * 68];
  __shared__ float Xl[64 * 65];
  const int lane = threadIdx.x;
  const int dir = blockIdx.y;
  for (int e = lane; e < 65 * 68; e += 64) MTl[e] = MT_g[e];
  __syncthreads();
  const int bx = blockIdx.x;
  const bool service = bx >= CHK;
  const int c = service ? bx - CHK : bx;
  int r0, r1;
  if (dir == 0){ r0 = 1 + c * LCH; r1 = min((c + 1) * LCH, T_LEN - 1); }
  else {
    int ue = min((c + 1) * LCH, T_LEN - 1) - 1;
    r0 = (T_LEN - 1) - ue; r1 = (T_LEN - 1) - c * LCH;
  }
  float* Sc = S + (size_t)(dir * CHK + c) * 4290;
  float* sig_out = Sc + 4225;

  if (!service){
    #pragma unroll
    for (int k = 0; k < 65; ++k) Xl[lane * 65 + k] = (k == lane) ? 1.f : 0.f;
    float rs = 1.f, sig = 0.f;
    float bvec = Bexp[(size_t)r0 * KP1 + lane];
    float b64  = Bexp[(size_t)r0 * KP1 + 64];
    for (int r = r0; r <= r1; ++r){
      float bvn = 0.f, b64n = 0.f;
      if (r < r1){
        bvn  = Bexp[(size_t)(r + 1) * KP1 + lane];
        b64n = Bexp[(size_t)(r + 1) * KP1 + 64];
      }
      float Xr[65];
      #pragma unroll
      for (int k = 0; k < 65; ++k) Xr[k] = Xl[lane * 65 + k] * rs;
      #pragma unroll
      for (int k = 0; k < 65; ++k) Xl[lane * 65 + k] = 0.f;
      unsigned long long mask = __ballot(bvec != 0.f);
      float cmax = 0.f;
      while (mask){
        int i = __builtin_ctzll(mask); mask &= mask - 1;
        float bi = readlane_f(bvec, i);
        const float* Mr = &MTl[i * 68];
        float a0 = 0.f, a1 = 0.f, a2 = 0.f, a3 = 0.f;
        #pragma unroll
        for (int g = 0; g < 16; ++g){
          float4 m4 = *reinterpret_cast<const float4*>(&Mr[g * 4]);
          a0 = fmaf(m4.x, Xr[g * 4 + 0], a0);
          a1 = fmaf(m4.y, Xr[g * 4 + 1], a1);
          a2 = fmaf(m4.z, Xr[g * 4 + 2], a2);
          a3 = fmaf(m4.w, Xr[g * 4 + 3], a3);
        }
        float sum = ((a0 + a1) + (a2 + a3)) + Mr[64] * Xr[64];
        float nv = bi * sum;
        Xl[lane * 65 + i] = nv;
        cmax = fmaxf(cmax, nv);
      }
      if (b64 != 0.f){
        const float* Mr = &MTl[64 * 68];
        float a0 = 0.f, a1 = 0.f, a2 = 0.f, a3 = 0.f;
        #pragma unroll
        for (int g = 0; g < 16; ++g){
          float4 m4 = *reinterpret_cast<const float4*>(&Mr[g * 4]);
          a0 = fmaf(m4.x, Xr[g * 4 + 0], a0);
          a1 = fmaf(m4.y, Xr[g * 4 + 1], a1);
          a2 = fmaf(m4.z, Xr[g * 4 + 2], a2);
          a3 = fmaf(m4.w, Xr[g * 4 + 3], a3);
        }
        float sum = ((a0 + a1) + (a2 + a3)) + Mr[64] * Xr[64];
        float nv = b64 * sum;
        Xl[lane * 65 + 64] = nv;
        cmax = fmaxf(cmax, nv);
      }
      float s = wmax64(cmax);
      s = fmaxf(s, 1e-37f);
      sig += logf(s);
      rs = 1.f / s;
      bvec = bvn; b64 = b64n;
    }
    for (int k = 0; k < 65; ++k) Sc[k * 65 + lane] = Xl[lane * 65 + k] * rs;
    sig_out[lane] = sig;   // lanes 0..63 (all equal)
  } else {
    // column 64: lane = k, v64 replicated
    float v = 0.f, v64 = 1.f, sig = 0.f;
    float bvec = Bexp[(size_t)r0 * KP1 + lane];
    float b64  = Bexp[(size_t)r0 * KP1 + 64];
    for (int r = r0; r <= r1; ++r){
      float bvn = 0.f, b64n = 0.f;
      if (r < r1){
        bvn  = Bexp[(size_t)(r + 1) * KP1 + lane];
        b64n = Bexp[(size_t)(r + 1) * KP1 + 64];
      }
      unsigned long long mask = __ballot(bvec != 0.f);
      float vn = 0.f, v64n = 0.f;
      while (mask){
        int i = __builtin_ctzll(mask); mask &= mask - 1;
        float mi = MTl[i * 68 + lane];          // M[k=lane][i]
        float t = mi * v;
        float sum = wsum64(t) + MTl[i * 68 + 64] * v64;
        float bi = readlane_f(bvec, i);
        vn = (lane == i) ? bi * sum : vn;
      }
      if (b64 != 0.f){
        float t = MTl[64 * 68 + lane] * v;      // M[k][64]
        float sum = wsum64(t) + MTl[64 * 68 + 64] * v64;
        v64n = b64 * sum;
      }
      float m = wmax64(vn);
      m = fmaxf(m, v64n);
      m = fmaxf(m, 1e-37f);
      float irs = 1.f / m;
      v = vn * irs; v64 = v64n * irs;
      sig += logf(m);
      bvec = bvn; b64 = b64n;
    }
    Sc[lane * 65 + 64] = v;          // X[k=lane][64]
    if (lane == 0){ Sc[64 * 65 + 64] = v64; sig_out[64] = sig; }
  }
}

// ---------------- phase 2: sequential seed propagation (2 blocks) ----------------
__global__ __launch_bounds__(256) void p2_k(const float* __restrict__ S,
    const float* __restrict__ M_mat, const float* __restrict__ Bexp,
    float* __restrict__ vstore){
  const int dir = blockIdx.x, tid = threadIdx.x;
  __shared__ float Sl[4290];
  __shared__ float vl[66];
  __shared__ float red[1];
  if (dir == 0){
    if (tid < 65) vl[tid] = M_mat[64 * 68 + tid] * Bexp[tid];  // (pi+eps) * Bexp row 0
  } else {
    if (tid < 65) vl[tid] = 1.f;
  }
  __syncthreads();
  if (tid < 64){
    float x = vl[tid];
    float s = wsum64(x) + vl[64];
    if (tid == 0) red[0] = 1.f / s;
  }
  __syncthreads();
  if (tid < 65) vl[tid] *= red[0];
  const float* Sg = S + (size_t)dir * CHK * 4290;
  float sb[17];
  #pragma unroll
  for (int u = 0; u < 17; ++u){
    int e = tid + 256 * u;
    sb[u] = (e < 4290) ? Sg[e] : 0.f;
  }
  for (int c = 0; c < CHK; ++c){
    __syncthreads();
    #pragma unroll
    for (int u = 0; u < 17; ++u){
      int e = tid + 256 * u;
      if (e < 4290) Sl[e] = sb[u];
    }
    __syncthreads();
    if (c + 1 < CHK){
      const float* Sn = Sg + (size_t)(c + 1) * 4290;
      #pragma unroll
      for (int u = 0; u < 17; ++u){
        int e = tid + 256 * u;
        sb[u] = (e < 4290) ? Sn[e] : 0.f;
      }
    }
    if (tid < 65){
      vstore[(size_t)(dir * CHK + c) * KP1 + tid] = vl[tid];
      float sm = fmaxf(Sl[4225], Sl[4225 + 64]);
      vl[tid] = vl[tid] * expf(Sl[4225 + tid] - sm);   // weights
    }
    __syncthreads();
    float vn = 0.f;
    if (tid < 65){
      if (dir == 0){
        for (int j = 0; j < 65; ++j) vn = fmaf(Sl[tid * 65 + j], vl[j], vn);
      } else {
        for (int k = 0; k < 65; ++k) vn = fmaf(Sl[k * 65 + tid], vl[k], vn);
      }
    }
    __syncthreads();
    if (tid < 65) vl[tid] = vn;
    __syncthreads();
    if (tid < 64){
      float x = vl[tid];
      float s = wsum64(x) + vl[64];
      if (tid == 0) red[0] = 1.f / fmaxf(s, 1e-37f);
    }
    __syncthreads();
    if (tid < 65) vl[tid] *= red[0];
  }
}

// ---------------- phase 3: per-chunk recompute of normalized p/q ----------------
__global__ __launch_bounds__(64) void p3_k(const float* __restrict__ M_mat,
    const float* __restrict__ MT_g, const float* __restrict__ Bexp,
    const float* __restrict__ bmax, const float* __restrict__ vstore,
    float* __restrict__ pstore, float* __restrict__ qstore,
    float* __restrict__ cfor, float* __restrict__ csum){
  __shared__ float Ml[65 * 68];
  const int lane = threadIdx.x;
  const int c = blockIdx.x, dir = blockIdx.y;
  const float* src = (dir == 0) ? M_mat : MT_g;
  for (int e = lane; e < 65 * 68; e += 64) Ml[e] = src[e];
  __syncthreads();
  if (dir == 0){
    float p, p64, sig;
    const int r0 = 1 + c * LCH, r1 = min((c + 1) * LCH, T_LEN - 1);
    if (c == 0){
      float pe = Ml[64 * 68 + lane], pe64 = Ml[64 * 68 + 64];
      float b = Bexp[lane], b64v = Bexp[64];
      float val = pe * b, v64 = pe64 * b64v;
      float s = wsum64(val) + v64;
      float rr = 1.f / s;
      p = val * rr; p64 = v64 * rr;
      pstore[lane] = p; if (lane == 0) pstore[64] = p64;
      sig = logf(s) + bmax[0];
      if (lane == 0) cfor[0] = sig;
    } else {
      p = vstore[(size_t)c * KP1 + lane];
      p64 = vstore[(size_t)c * KP1 + 64];
      sig = 0.f;
    }
    float bvec = Bexp[(size_t)r0 * KP1 + lane], b64 = Bexp[(size_t)r0 * KP1 + 64];
    for (int r = r0; r <= r1; ++r){
      float bvn = 0.f, b64n = 0.f;
      if (r < r1){
        bvn = Bexp[(size_t)(r + 1) * KP1 + lane]; b64n = Bexp[(size_t)(r + 1) * KP1 + 64];
      }
      unsigned long long mask = __ballot(p != 0.f);
      float msg = 0.f, msg64 = 0.f;
      while (mask){
        int i = __builtin_ctzll(mask); mask &= mask - 1;
        float pi_ = readlane_f(p, i);
        msg   = fmaf(pi_, Ml[i * 68 + lane], msg);   // M[i][j=lane]
        msg64 = fmaf(pi_, Ml[i * 68 + 64], msg64);   // M[i][64]
      }
      if (p64 != 0.f){
        msg   = fmaf(p64, Ml[64 * 68 + lane], msg);
        msg64 = fmaf(p64, Ml[64 * 68 + 64], msg64);
      }
      float val = bvec * msg, v64 = b64 * msg64;
      float s = wsum64(val) + v64;
      float rr = 1.f / s;
      p = val * rr; p64 = v64 * rr;
      pstore[(size_t)r * KP1 + lane] = p;
      if (lane == 0) pstore[(size_t)r * KP1 + 64] = p64;
      sig += logf(s) + bmax[r];
      if (lane == 0) cfor[r] = sig;
      bvec = bvn; b64 = b64n;
    }
    if (lane == 0) csum[c] = sig;
  } else {
    float q, q64;
    const int ustart = c * LCH;
    const int ue = min((c + 1) * LCH, T_LEN - 1) - 1;
    if (c == 0){
      q = 1.f / 65.f; q64 = 1.f / 65.f;
      qstore[(size_t)(T_LEN - 1) * KP1 + lane] = q;
      if (lane == 0) qstore[(size_t)(T_LEN - 1) * KP1 + 64] = q64;
    } else {
      q = vstore[(size_t)(CHK + c) * KP1 + lane];
      q64 = vstore[(size_t)(CHK + c) * KP1 + 64];
    }
    int rfirst = (T_LEN - 1) - ustart;
    float bvec = Bexp[(size_t)rfirst * KP1 + lane], b64 = Bexp[(size_t)rfirst * KP1 + 64];
    for (int u = ustart; u <= ue; ++u){
      int r = (T_LEN - 1) - u;
      float bvn = 0.f, b64n = 0.f;
      if (u < ue){
        bvn = Bexp[(size_t)(r - 1) * KP1 + lane]; b64n = Bexp[(size_t)(r - 1) * KP1 + 64];
      }
      float x = bvec * q, x64 = b64 * q64;
      unsigned long long mask = __ballot(x != 0.f);
      float acc = 0.f, acc64 = 0.f;
      while (mask){
        int k = __builtin_ctzll(mask); mask &= mask - 1;
        float xk = readlane_f(x, k);
        acc   = fmaf(xk, Ml[k * 68 + lane], acc);    // MT[k][j=lane] = M[j][k]
        acc64 = fmaf(xk, Ml[k * 68 + 64], acc64);    // MT[k][64] = M[64][k]
      }
      if (x64 != 0.f){
        acc   = fmaf(x64, Ml[64 * 68 + lane], acc);  // M[j][64]
        acc64 = fmaf(x64, Ml[64 * 68 + 64], acc64);  // M[64][64]
      }
      float s = wsum64(acc) + acc64;
      float rr = 1.f / s;
      q = acc * rr; q64 = acc64 * rr;
      qstore[(size_t)(r - 1) * KP1 + lane] = q;
      if (lane == 0) qstore[(size_t)(r - 1) * KP1 + 64] = q64;
      bvec = bvn; b64 = b64n;
    }
  }
}

// ---------------- prefix over chunk sums + logZ ----------------
__global__ __launch_bounds__(64) void pfx_k(const float* __restrict__ csum,
    float* __restrict__ coff, float* __restrict__ logZ){
  __shared__ float cs[CHK], co[CHK + 1];
  const int lane = threadIdx.x;
  for (int e = lane; e < CHK; e += 64) cs[e] = csum[e];
  __syncthreads();
  if (lane == 0){
    float a = 0.f;
    for (int c = 0; c < CHK; ++c){ co[c] = a; a += cs[c]; }
    co[CHK] = a;
    logZ[0] = a;
  }
  __syncthreads();
  for (int e = lane; e < CHK; e += 64) coff[e] = co[e];
}

__global__ void off_k(float* __restrict__ cfor, const float* __restrict__ coff){
  int t = blockIdx.x * 256 + threadIdx.x;
  if (t >= T_LEN) return;
  int c = (t == 0) ? 0 : (t - 1) / LCH;
  cfor[t] += coff[c];
}

// ---------------- gamma ----------------
__global__ void gamma_k(const float* __restrict__ pstore, const float* __restrict__ qstore,
                        float* __restrict__ gout){
  const int lane = threadIdx.x & 63, w = threadIdx.x >> 6;
  const int t = blockIdx.x * 4 + w;
  if (t >= T_LEN) return;
  float a   = pstore[(size_t)t * KP1 + lane] * qstore[(size_t)t * KP1 + lane];
  float a64 = pstore[(size_t)t * KP1 + 64]   * qstore[(size_t)t * KP1 + 64];
  float s = wsum64(a) + a64;
  float r = rcp_nr(s);
  gout[(size_t)t * KP1 + lane] = a * r;
  if (lane == 0) gout[(size_t)t * KP1 + 64] = a64 * r;
}

// ---------------- xi ----------------
__global__ void xi_k(const float* __restrict__ pstore, const float* __restrict__ qstore,
                     const float* __restrict__ logB, const float* __restrict__ cfor,
                     const float* __restrict__ logA, const float* __restrict__ logpi,
                     float* __restrict__ xiout){
  const int t = blockIdx.x, tid = threadIdx.x;
  __shared__ float laS[64], bbS[KP1], lpiS[KP1];
  __shared__ float red[4], red2[4];
  if (tid < 64){
    laS[tid] = logf(pstore[(size_t)t * KP1 + tid]) + cfor[t];
  } else if (tid < 64 + KP1){
    int j = tid - 64;
    bbS[j] = logB[(size_t)(t + 1) * KP1 + j] + logf(qstore[(size_t)(t + 1) * KP1 + j]);
  } else if (tid < 64 + 2 * KP1){
    int j = tid - (64 + KP1);
    lpiS[j] = logpi[j];
  }
  __syncthreads();
  float tv[17];
  float lm = -3.0e38f;
  #pragma unroll
  for (int r2 = 0; r2 < 17; ++r2){
    int e = tid + 256 * r2;
    if (e < KST * KP1){
      int i = e / KP1;
      int j = e - i * KP1;
      float a = laS[i] + logA[e];
      float b = lpiS[j];
      float mx = fmaxf(a, b), mn = fminf(a, b);
      float v = bbS[j] + mx + log1pf(expf(mn - mx));
      tv[r2] = v;
      lm = fmaxf(lm, v);
    } else tv[r2] = -3.0e38f;
  }
  lm = wmax64(lm);
  if ((tid & 63) == 0) red[tid >> 6] = lm;
  __syncthreads();
  float gm = fmaxf(fmaxf(red[0], red[1]), fmaxf(red[2], red[3]));
  float se = 0.f;
  #pragma unroll
  for (int r2 = 0; r2 < 17; ++r2) se += expf(tv[r2] - gm);
  se = wsum64(se);
  if ((tid & 63) == 0) red2[tid >> 6] = se;
  __syncthreads();
  float S = red2[0] + red2[1] + red2[2] + red2[3];
  float rS = rcp_nr(S);
  float* xrow = xiout + (size_t)t * (KST * KP1);
  #pragma unroll
  for (int r2 = 0; r2 < 17; ++r2){
    int e = tid + 256 * r2;
    if (e < KST * KP1) xrow[e] = expf(tv[r2] - gm) * rS;
  }
}

extern "C" void kernel_launch(void* const* d_in, const int* in_sizes, int n_in,
                              void* d_out, int out_size, void* d_ws, size_t ws_size,
                              hipStream_t stream){
  const float* z_mu  = (const float*)d_in[0];
  const float* z_var = (const float*)d_in[1];
  const float* mu    = (const float*)d_in[2];
  const float* kappa = (const float*)d_in[3];
  const float* nu    = (const float*)d_in[4];
  const float* Psi   = (const float*)d_in[5];
  const float* phi   = (const float*)d_in[6];
  const float* pis   = (const float*)d_in[7];
  float* out = (float*)d_out;

  float* ws     = (float*)d_ws;
  float* Lam    = ws;                  // 66560
  float* dLam   = Lam + 66560;         // 2080
  float* constk = dLam + 2080;         // 65
  float* M_mat  = constk + 65;         // 4420
  float* MT     = M_mat + 4420;        // 4420
  float* logA   = MT + 4420;           // 4160
  float* logpi  = logA + 4160;         // 65
  float* logB   = logpi + 65;          // 1,300,000
  float* Bexp   = logB + 1300000;      // 1,300,000
  float* bmax   = Bexp + 1300000;      // 20,000
  float* pstore = bmax + 20000;        // 1,300,000
  float* qstore = pstore + 1300000;    // 1,300,000
  float* cfor   = qstore + 1300000;    // 20,000
  float* S      = cfor + 20000;        // 2*250*4290 = 2,145,000
  float* vstore = S + 2145000;         // 2*250*65 = 32,500
  float* csum   = vstore + 32500;      // 256
  float* coff   = csum + 256;          // 256
  // total ~ 7.5M floats ~ 30 MiB

  float* gammaOut = out;
  float* xiOut    = gammaOut + (size_t)T_LEN * KP1;
  float* logZOut  = xiOut + (size_t)(T_LEN - 1) * KST * KP1;

  prep_k<<<KP1, 64, 0, stream>>>(mu, kappa, nu, Psi, Lam, dLam, constk);
  prep_trans<<<1, 64, 0, stream>>>(phi, pis, M_mat, MT, logA, logpi);
  logb_k<<<dim3((T_LEN + 255) / 256, KP1), 256, 0, stream>>>(z_mu, z_var, mu, Lam, dLam, constk, logB);
  bexp_k<<<(T_LEN + 3) / 4, 256, 0, stream>>>(logB, Bexp, bmax);
  p1_k<<<dim3(2 * CHK, 2), 64, 0, stream>>>(MT, Bexp, S);
  p2_k<<<2, 256, 0, stream>>>(S, M_mat, Bexp, vstore);
  p3_k<<<dim3(CHK, 2), 64, 0, stream>>>(M_mat, MT, Bexp, bmax, vstore, pstore, qstore, cfor, csum);
  pfx_k<<<1, 64, 0, stream>>>(csum, coff, logZOut);
  off_k<<<(T_LEN + 255) / 256, 256, 0, stream>>>(cfor, coff);
  gamma_k<<<(T_LEN + 3) / 4, 256, 0, stream>>>(pstore, qstore, gammaOut);
  xi_k<<<T_LEN - 1, 256, 0, stream>>>(pstore, qstore, logB, cfor, logA, logpi, xiOut);
}